// Round 7
// baseline (538.553 us; speedup 1.0000x reference)
//
#include <hip/hip_runtime.h>
#include <hip/hip_bf16.h>
#include <stdint.h>

typedef __bf16 bf16_t;
typedef __bf16 bf16x8 __attribute__((ext_vector_type(8)));
typedef __bf16 bf16x4v __attribute__((ext_vector_type(4)));
typedef float f32x4 __attribute__((ext_vector_type(4)));

#define MFMA16(A, B, C) __builtin_amdgcn_mfma_f32_16x16x32_bf16((A), (B), (C), 0, 0, 0)

// Problem constants
#define BB 2
#define SS 2048
#define DD 1024
#define HH 16
#define DH 64
#define MM (BB * SS)          // 4096 rows

// async global->LDS, 16B per lane. LDS dest must be wave-uniform base
// (HW adds lane*16); global src is per-lane.
__device__ __forceinline__ void load_lds16(const void* g, void* l) {
  __builtin_amdgcn_global_load_lds(
      (const __attribute__((address_space(1))) void*)g,
      (__attribute__((address_space(3))) void*)l, 16, 0, 0);
}

__device__ __forceinline__ float fast_exp2(float x) {
  float r;
  asm("v_exp_f32 %0, %1" : "=v"(r) : "v"(x));
  return r;
}
__device__ __forceinline__ uint32_t cvt_pk_bf16(float lo, float hi) {
  uint32_t u;
  asm("v_cvt_pk_bf16_f32 %0, %1, %2" : "=v"(u) : "v"(lo), "v"(hi));
  return u;
}

// ---------------- prep kernels ----------------

__global__ __launch_bounds__(256) void cvt_f32_to_bf16(const float* __restrict__ in,
                                                       bf16_t* __restrict__ out, int n4) {
  int i = blockIdx.x * blockDim.x + threadIdx.x;
  if (i >= n4) return;
  float4 v = reinterpret_cast<const float4*>(in)[i];
  bf16x4v o;
  o[0] = (bf16_t)v.x; o[1] = (bf16_t)v.y; o[2] = (bf16_t)v.z; o[3] = (bf16_t)v.w;
  reinterpret_cast<bf16x4v*>(out)[i] = o;
}

// W[K][N] (fp32) -> WT[N][K] (bf16)
__global__ void transpose_f32_to_bf16(const float* __restrict__ W, bf16_t* __restrict__ WT,
                                      int K, int N) {
  __shared__ float tile[32][33];
  int n0 = blockIdx.x * 32, k0 = blockIdx.y * 32;
  int tx = threadIdx.x, ty = threadIdx.y;
  #pragma unroll
  for (int i = ty; i < 32; i += 8) tile[i][tx] = W[(size_t)(k0 + i) * N + n0 + tx];
  __syncthreads();
  #pragma unroll
  for (int i = ty; i < 32; i += 8) WT[(size_t)(n0 + i) * K + k0 + tx] = (bf16_t)tile[tx][i];
}

// ---------------- GEMM v2 (unchanged from round 6) ----------------
template <int BM, int BN, int WGM, int WGN, int EPI>
__global__ __launch_bounds__(512) void gemm2(
    const bf16_t* __restrict__ A, const bf16_t* __restrict__ BT,
    const float* __restrict__ bias, float* __restrict__ outf,
    bf16_t* __restrict__ q_b, bf16_t* __restrict__ k_b, bf16_t* __restrict__ vt_b,
    int M, int N, int K) {
  constexpr int BK = 64;
  constexpr int MF = BM / WGM / 16;
  constexpr int NF = BN / WGN / 16;
  constexpr int RS = BM / WGM;
  constexpr int CS = BN / WGN;
  constexpr int LA = BM * BK * 2 / (512 * 16);
  constexpr int LB = BN * BK * 2 / (512 * 16);

  __shared__ __align__(16) bf16_t At[2][BM * BK];
  __shared__ __align__(16) bf16_t Bt[2][BN * BK];

  const int tid = threadIdx.x;
  const int l = tid & 63, w = tid >> 6;
  const int lr = l & 15, lg = l >> 4;
  const int wr = w / WGN, wc = w % WGN;
  const int row0 = blockIdx.y * BM, col0 = blockIdx.x * BN;

  auto stage = [&](int buf, int k0) {
    #pragma unroll
    for (int i = 0; i < LA; ++i) {
      int e = (tid + i * 512) * 8;
      int r = e >> 6, c = e & 63;
      int cs = ((c * 2) ^ ((r & 7) << 4)) >> 1;
      load_lds16(&A[(size_t)(row0 + r) * K + k0 + cs], &At[buf][(w * 64 + i * 512) * 8]);
    }
    #pragma unroll
    for (int i = 0; i < LB; ++i) {
      int e = (tid + i * 512) * 8;
      int r = e >> 6, c = e & 63;
      int cs = ((c * 2) ^ ((r & 7) << 4)) >> 1;
      load_lds16(&BT[(size_t)(col0 + r) * K + k0 + cs], &Bt[buf][(w * 64 + i * 512) * 8]);
    }
  };

  f32x4 vz = {0.f, 0.f, 0.f, 0.f};
  f32x4 acc[MF][NF];
  #pragma unroll
  for (int m = 0; m < MF; ++m)
    #pragma unroll
    for (int n = 0; n < NF; ++n) acc[m][n] = vz;

  const int sw = (lr & 7) << 4;
  const int nk = K / BK;
  stage(0, 0);
  __syncthreads();
  int cur = 0;
  for (int k = 0; k < nk; ++k) {
    if (k + 1 < nk) stage(cur ^ 1, (k + 1) * BK);
    #pragma unroll
    for (int kk = 0; kk < 2; ++kk) {
      const int rdo = (kk * 64 + lg * 16) ^ sw;
      bf16x8 af[MF], bfr[NF];
      #pragma unroll
      for (int m = 0; m < MF; ++m) {
        int row = wr * RS + m * 16 + lr;
        af[m] = *(const bf16x8*)((const char*)&At[cur][0] + row * 128 + rdo);
      }
      #pragma unroll
      for (int n = 0; n < NF; ++n) {
        int brow = wc * CS + n * 16 + lr;
        bfr[n] = *(const bf16x8*)((const char*)&Bt[cur][0] + brow * 128 + rdo);
      }
      #pragma unroll
      for (int m = 0; m < MF; ++m)
        #pragma unroll
        for (int n = 0; n < NF; ++n) acc[m][n] = MFMA16(af[m], bfr[n], acc[m][n]);
    }
    __syncthreads();
    cur ^= 1;
  }

  #pragma unroll
  for (int m = 0; m < MF; ++m) {
    int rl = wr * RS + m * 16 + lg * 4;
    #pragma unroll
    for (int n = 0; n < NF; ++n) {
      int col = col0 + wc * CS + n * 16 + lr;
      float bz = bias[col];
      #pragma unroll
      for (int r = 0; r < 4; ++r) {
        int row = row0 + rl + r;
        float v = acc[m][n][r] + bz;
        if (EPI == 1) {
          outf[(size_t)row * N + col] = v;
        } else {
          int b = row >> 11, s = row & 2047;
          int part = col >> 10, d = col & 1023;
          int h = d >> 6, dh = d & 63;
          size_t idx = ((size_t)(b * HH + h) * SS + s) * DH + dh;
          if (part == 0) {
            q_b[idx] = (bf16_t)v;
          } else if (part == 1) {
            k_b[idx] = (bf16_t)v;
            outf[(((size_t)(b * 2 + 0) * HH + h) * SS + s) * DH + dh] = v;  // present K
          } else {
            vt_b[((size_t)(b * HH + h) * DH + dh) * SS + s] = (bf16_t)v;   // V transposed
            outf[(((size_t)(b * 2 + 1) * HH + h) * SS + s) * DH + dh] = v;  // present V
          }
        }
      }
    }
  }
}

// ---------------- flash attention: balanced band-pair version ----------------
// grid: x = j (0..15 band pairs), y = B*H. Bands of 64 q-rows; block j owns
// band pair (j, 31-j), interleaved: wave frag0 = long band (31-j), frag1 =
// short band (j), active while t <= j. Weighted work = 33 tile-frags per
// block, constant -> no causal tail. 512 blocks, 2/CU, all co-resident.
__global__ __launch_bounds__(256) void attn_fwd(
    const bf16_t* __restrict__ q_b, const bf16_t* __restrict__ k_b,
    const bf16_t* __restrict__ vt_b, bf16_t* __restrict__ attn_out) {
  __shared__ __align__(16) bf16_t Kt[2][64 * 64];        // [kv][d] 2x8KB
  __shared__ __align__(16) bf16_t Vt[2][64 * 64];        // [d][kv] 2x8KB
  __shared__ __align__(16) bf16_t P_lds[4][32][72];      // [wave][frag*16+q][kv]+pad

  const int bh = blockIdx.y;
  const int j = blockIdx.x;               // pair index; heaviest (j=0) first
  const int qlb = (31 - j) * 64;          // long band base
  const int qsb = j * 64;                 // short band base
  const int tid = threadIdx.x;
  const int w = tid >> 6, l = tid & 63;
  const int lr = l & 15, lg = l >> 4;

  const bf16_t* qb = q_b + (size_t)bh * SS * DH;
  const bf16_t* kb = k_b + (size_t)bh * SS * DH;
  const bf16_t* vt = vt_b + (size_t)bh * DH * SS;

  const int r0 = tid >> 3;
  const int cs = (((tid & 7) * 16) ^ ((r0 & 7) << 4)) >> 1;
  const bf16_t* gk0 = kb + r0 * DH + cs;
  const bf16_t* gk1 = gk0 + 32 * DH;
  const bf16_t* gv0 = vt + (size_t)r0 * SS + cs;
  const bf16_t* gv1 = gv0 + 32 * SS;
  auto stageKV = [&](int buf) {  // stages the NEXT sequential kv tile
    bf16_t* lk = &Kt[buf][w * 512];
    load_lds16(gk0, lk);
    load_lds16(gk1, lk + 2048);
    bf16_t* lv = &Vt[buf][w * 512];
    load_lds16(gv0, lv);
    load_lds16(gv1, lv + 2048);
    gk0 += 64 * DH; gk1 += 64 * DH; gv0 += 64; gv1 += 64;
  };

  const int qrow0 = qlb + w * 16 + lr;  // frag 0: long band
  const int qrow1 = qsb + w * 16 + lr;  // frag 1: short band
  bf16x8 qf[2][2];
  qf[0][0] = *(const bf16x8*)&qb[(size_t)qrow0 * DH + lg * 8];
  qf[0][1] = *(const bf16x8*)&qb[(size_t)qrow0 * DH + 32 + lg * 8];
  qf[1][0] = *(const bf16x8*)&qb[(size_t)qrow1 * DH + lg * 8];
  qf[1][1] = *(const bf16x8*)&qb[(size_t)qrow1 * DH + 32 + lg * 8];

  bf16x8 ones;
  #pragma unroll
  for (int jj = 0; jj < 8; ++jj) ones[jj] = (bf16_t)1.0f;

  f32x4 vzero = {0.f, 0.f, 0.f, 0.f};
  f32x4 oacc[2][4];
  #pragma unroll
  for (int q = 0; q < 2; ++q)
    #pragma unroll
    for (int d = 0; d < 4; ++d) oacc[q][d] = vzero;
  float m_run[2] = {-1e30f, -1e30f}, l_run[2] = {0.f, 0.f};

  const float SCL = 0.125f * 1.4426950408889634f;  // 1/sqrt(64) * log2(e)
  const int sw = (lr & 7) << 4;
  const int rd0 = (lg * 16) ^ sw;
  const int rd1 = (64 + lg * 16) ^ sw;

  const int nkv = 32 - j;  // tiles for the long band
  stageKV(0);
  __syncthreads();
  int cur = 0;
  for (int t = 0; t < nkv; ++t) {
    const int kv0 = t * 64;
    if (t + 1 < nkv) stageKV(cur ^ 1);  // prefetch next tile
    const bool act1 = (t <= j);         // short band active (wave-uniform)

    // ---- QK^T (swapped): lane col = q, D-row = kv; RAW scores ----
    float sc[2][4][4];
    #pragma unroll
    for (int kvf = 0; kvf < 4; ++kvf) {
      const char* kbase = (const char*)&Kt[cur][0] + (kvf * 16 + lr) * 128;
      bf16x8 kf0 = *(const bf16x8*)(kbase + rd0);
      bf16x8 kf1 = *(const bf16x8*)(kbase + rd1);
      {
        f32x4 a = vzero;
        a = MFMA16(kf0, qf[0][0], a);
        a = MFMA16(kf1, qf[0][1], a);
        #pragma unroll
        for (int r = 0; r < 4; ++r) sc[0][kvf][r] = a[r];
      }
      if (act1) {
        f32x4 a = vzero;
        a = MFMA16(kf0, qf[1][0], a);
        a = MFMA16(kf1, qf[1][1], a);
        #pragma unroll
        for (int r = 0; r < 4; ++r) sc[1][kvf][r] = a[r];
      }
    }
    // causal masks (wave-uniform gates; trigger only on diagonal tiles)
    if (kv0 + 63 > qlb + w * 16) {
      int dthr = qrow0 - kv0;
      #pragma unroll
      for (int kvf = 0; kvf < 4; ++kvf)
        #pragma unroll
        for (int r = 0; r < 4; ++r) {
          int kvl = kvf * 16 + lg * 4 + r;
          if (kvl > dthr) sc[0][kvf][r] = -1e30f;
        }
    }
    if (act1 && kv0 + 63 > qsb + w * 16) {
      int dthr = qrow1 - kv0;
      #pragma unroll
      for (int kvf = 0; kvf < 4; ++kvf)
        #pragma unroll
        for (int r = 0; r < 4; ++r) {
          int kvl = kvf * 16 + lg * 4 + r;
          if (kvl > dthr) sc[1][kvf][r] = -1e30f;
        }
    }

    // ---- online softmax per active frag, raw domain ----
    const int nq = act1 ? 2 : 1;
    for (int q = 0; q < nq; ++q) {
      float tm = fmaxf(fmaxf(sc[q][0][0], sc[q][0][1]), sc[q][0][2]);
      tm = fmaxf(fmaxf(tm, sc[q][0][3]), sc[q][1][0]);
      tm = fmaxf(fmaxf(tm, sc[q][1][1]), sc[q][1][2]);
      tm = fmaxf(fmaxf(tm, sc[q][1][3]), sc[q][2][0]);
      tm = fmaxf(fmaxf(tm, sc[q][2][1]), sc[q][2][2]);
      tm = fmaxf(fmaxf(tm, sc[q][2][3]), sc[q][3][0]);
      tm = fmaxf(fmaxf(tm, sc[q][3][1]), sc[q][3][2]);
      tm = fmaxf(tm, sc[q][3][3]);
      tm = fmaxf(tm, __shfl_xor(tm, 16));
      tm = fmaxf(tm, __shfl_xor(tm, 32));
      if (!__all(tm <= m_run[q] + 44.0f)) {   // defer-max (T13)
        float mnew = fmaxf(m_run[q], tm);
        float alpha = fast_exp2((m_run[q] - mnew) * SCL);
        l_run[q] *= alpha;
        #pragma unroll
        for (int d = 0; d < 4; ++d) oacc[q][d] *= alpha;
        m_run[q] = mnew;
      }
      float mneg = m_run[q] * (-SCL);
      #pragma unroll
      for (int kvf = 0; kvf < 4; ++kvf) {
        float p0 = fast_exp2(__builtin_fmaf(sc[q][kvf][0], SCL, mneg));
        float p1 = fast_exp2(__builtin_fmaf(sc[q][kvf][1], SCL, mneg));
        float p2 = fast_exp2(__builtin_fmaf(sc[q][kvf][2], SCL, mneg));
        float p3 = fast_exp2(__builtin_fmaf(sc[q][kvf][3], SCL, mneg));
        uint2 pk;
        pk.x = cvt_pk_bf16(p0, p1);
        pk.y = cvt_pk_bf16(p2, p3);
        *(uint2*)&P_lds[w][q * 16 + lr][kvf * 16 + lg * 4] = pk;
      }
    }

    // ---- read P frags; l-sum via ones-MFMA; PV (T5 setprio) ----
    bf16x8 pf[2][2];
    for (int q = 0; q < nq; ++q) {
      pf[q][0] = *(const bf16x8*)&P_lds[w][q * 16 + lr][lg * 8];
      pf[q][1] = *(const bf16x8*)&P_lds[w][q * 16 + lr][32 + lg * 8];
      f32x4 ls = vzero;
      ls = MFMA16(ones, pf[q][0], ls);
      ls = MFMA16(ones, pf[q][1], ls);
      l_run[q] += ls[0];
    }
    __builtin_amdgcn_s_setprio(1);
    #pragma unroll
    for (int d = 0; d < 4; ++d) {
      const char* vbase = (const char*)&Vt[cur][0] + (d * 16 + lr) * 128;
      bf16x8 vf0 = *(const bf16x8*)(vbase + rd0);
      bf16x8 vf1 = *(const bf16x8*)(vbase + rd1);
      oacc[0][d] = MFMA16(vf0, pf[0][0], oacc[0][d]);
      oacc[0][d] = MFMA16(vf1, pf[0][1], oacc[0][d]);
      if (act1) {
        oacc[1][d] = MFMA16(vf0, pf[1][0], oacc[1][d]);
        oacc[1][d] = MFMA16(vf1, pf[1][1], oacc[1][d]);
      }
    }
    __builtin_amdgcn_s_setprio(0);
    __syncthreads();
    cur ^= 1;
  }

  // ---- epilogue: merge heads into [B*S, D] bf16 ----
  const int b = bh >> 4, h = bh & 15;
  #pragma unroll
  for (int q = 0; q < 2; ++q) {
    float inv_l = 1.f / l_run[q];
    int qrow = q ? qrow1 : qrow0;
    #pragma unroll
    for (int d = 0; d < 4; ++d)
      #pragma unroll
      for (int r = 0; r < 4; ++r) {
        int dd = d * 16 + lg * 4 + r;
        attn_out[((size_t)(b * SS + qrow)) * DD + h * DH + dd] =
            (bf16_t)(oacc[q][d][r] * inv_l);
      }
  }
}

// ---------------- launcher ----------------
extern "C" void kernel_launch(void* const* d_in, const int* in_sizes, int n_in,
                              void* d_out, int out_size, void* d_ws, size_t ws_size,
                              hipStream_t stream) {
  const float* x = (const float*)d_in[0];
  const float* c_attn_w = (const float*)d_in[1];
  const float* c_attn_b = (const float*)d_in[2];
  const float* c_proj_w = (const float*)d_in[3];
  const float* c_proj_b = (const float*)d_in[4];

  float* out = (float*)d_out;                       // a: [B,S,D]
  float* present = out + (size_t)BB * SS * DD;      // present: [B,2,H,S,Dh]

  char* ws = (char*)d_ws;
  bf16_t* xb     = (bf16_t*)(ws + 0);               //  8.4 MB  x as bf16 [M,K]
  bf16_t* wqkvT  = (bf16_t*)(ws + 8388608);         //  6.3 MB  [3072,1024]
  bf16_t* wprojT = (bf16_t*)(ws + 14680064);        //  2.1 MB  [1024,1024]
  bf16_t* q_b    = (bf16_t*)(ws + 16777216);        //  8.4 MB  [B,H,S,64]
  bf16_t* k_b    = (bf16_t*)(ws + 25165824);        //  8.4 MB  [B,H,S,64]
  bf16_t* vt_b   = (bf16_t*)(ws + 33554432);        //  8.4 MB  [B,H,64,S]
  bf16_t* attn_o = (bf16_t*)(ws + 41943040);        //  8.4 MB  [M,D]

  // 1. x -> bf16
  cvt_f32_to_bf16<<<(MM * DD / 4 + 255) / 256, 256, 0, stream>>>(x, xb, MM * DD / 4);
  // 2. weight transposes
  transpose_f32_to_bf16<<<dim3(3 * DD / 32, DD / 32), dim3(32, 8), 0, stream>>>(
      c_attn_w, wqkvT, DD, 3 * DD);
  transpose_f32_to_bf16<<<dim3(DD / 32, DD / 32), dim3(32, 8), 0, stream>>>(
      c_proj_w, wprojT, DD, DD);
  // 3. QKV GEMM [4096,1024]x[1024,3072]: 256x192 tile, grid 16x16 = 256 blocks
  gemm2<256, 192, 4, 2, 0><<<dim3(3 * DD / 192, MM / 256), 512, 0, stream>>>(
      xb, wqkvT, c_attn_b, present, q_b, k_b, vt_b, MM, 3 * DD, DD);
  // 4. flash attention: 16 balanced band-pairs x 32 (b,h)
  attn_fwd<<<dim3(16, BB * HH), 256, 0, stream>>>(q_b, k_b, vt_b, attn_o);
  // 5. output projection [4096,1024]x[1024,1024]: 128x128 tile, grid 256 blocks
  gemm2<128, 128, 2, 4, 1><<<dim3(DD / 128, MM / 128), 512, 0, stream>>>(
      attn_o, wprojT, c_proj_b, out, nullptr, nullptr, nullptr, MM, DD, DD);
}

// Round 8
// 212.723 us; speedup vs baseline: 2.5317x; 2.5317x over previous
//
#include <hip/hip_runtime.h>
#include <hip/hip_bf16.h>
#include <stdint.h>

typedef __bf16 bf16_t;
typedef __bf16 bf16x8 __attribute__((ext_vector_type(8)));
typedef __bf16 bf16x4v __attribute__((ext_vector_type(4)));
typedef float f32x4 __attribute__((ext_vector_type(4)));

#define MFMA16(A, B, C) __builtin_amdgcn_mfma_f32_16x16x32_bf16((A), (B), (C), 0, 0, 0)

// Problem constants
#define BB 2
#define SS 2048
#define DD 1024
#define HH 16
#define DH 64
#define MM (BB * SS)          // 4096 rows

template <int Q> struct QTag { static constexpr int v = Q; };

// async global->LDS, 16B per lane. LDS dest must be wave-uniform base
// (HW adds lane*16); global src is per-lane.
__device__ __forceinline__ void load_lds16(const void* g, void* l) {
  __builtin_amdgcn_global_load_lds(
      (const __attribute__((address_space(1))) void*)g,
      (__attribute__((address_space(3))) void*)l, 16, 0, 0);
}

__device__ __forceinline__ float fast_exp2(float x) {
  float r;
  asm("v_exp_f32 %0, %1" : "=v"(r) : "v"(x));
  return r;
}
__device__ __forceinline__ uint32_t cvt_pk_bf16(float lo, float hi) {
  uint32_t u;
  asm("v_cvt_pk_bf16_f32 %0, %1, %2" : "=v"(u) : "v"(lo), "v"(hi));
  return u;
}

// ---------------- prep kernels ----------------

__global__ __launch_bounds__(256) void cvt_f32_to_bf16(const float* __restrict__ in,
                                                       bf16_t* __restrict__ out, int n4) {
  int i = blockIdx.x * blockDim.x + threadIdx.x;
  if (i >= n4) return;
  float4 v = reinterpret_cast<const float4*>(in)[i];
  bf16x4v o;
  o[0] = (bf16_t)v.x; o[1] = (bf16_t)v.y; o[2] = (bf16_t)v.z; o[3] = (bf16_t)v.w;
  reinterpret_cast<bf16x4v*>(out)[i] = o;
}

// W[K][N] (fp32) -> WT[N][K] (bf16)
__global__ void transpose_f32_to_bf16(const float* __restrict__ W, bf16_t* __restrict__ WT,
                                      int K, int N) {
  __shared__ float tile[32][33];
  int n0 = blockIdx.x * 32, k0 = blockIdx.y * 32;
  int tx = threadIdx.x, ty = threadIdx.y;
  #pragma unroll
  for (int i = ty; i < 32; i += 8) tile[i][tx] = W[(size_t)(k0 + i) * N + n0 + tx];
  __syncthreads();
  #pragma unroll
  for (int i = ty; i < 32; i += 8) WT[(size_t)(n0 + i) * K + k0 + tx] = (bf16_t)tile[tx][i];
}

// ---------------- GEMM v2 (unchanged from round 6) ----------------
template <int BM, int BN, int WGM, int WGN, int EPI>
__global__ __launch_bounds__(512) void gemm2(
    const bf16_t* __restrict__ A, const bf16_t* __restrict__ BT,
    const float* __restrict__ bias, float* __restrict__ outf,
    bf16_t* __restrict__ q_b, bf16_t* __restrict__ k_b, bf16_t* __restrict__ vt_b,
    int M, int N, int K) {
  constexpr int BK = 64;
  constexpr int MF = BM / WGM / 16;
  constexpr int NF = BN / WGN / 16;
  constexpr int RS = BM / WGM;
  constexpr int CS = BN / WGN;
  constexpr int LA = BM * BK * 2 / (512 * 16);
  constexpr int LB = BN * BK * 2 / (512 * 16);

  __shared__ __align__(16) bf16_t At[2][BM * BK];
  __shared__ __align__(16) bf16_t Bt[2][BN * BK];

  const int tid = threadIdx.x;
  const int l = tid & 63, w = tid >> 6;
  const int lr = l & 15, lg = l >> 4;
  const int wr = w / WGN, wc = w % WGN;
  const int row0 = blockIdx.y * BM, col0 = blockIdx.x * BN;

  auto stage = [&](int buf, int k0) {
    #pragma unroll
    for (int i = 0; i < LA; ++i) {
      int e = (tid + i * 512) * 8;
      int r = e >> 6, c = e & 63;
      int cs = ((c * 2) ^ ((r & 7) << 4)) >> 1;
      load_lds16(&A[(size_t)(row0 + r) * K + k0 + cs], &At[buf][(w * 64 + i * 512) * 8]);
    }
    #pragma unroll
    for (int i = 0; i < LB; ++i) {
      int e = (tid + i * 512) * 8;
      int r = e >> 6, c = e & 63;
      int cs = ((c * 2) ^ ((r & 7) << 4)) >> 1;
      load_lds16(&BT[(size_t)(col0 + r) * K + k0 + cs], &Bt[buf][(w * 64 + i * 512) * 8]);
    }
  };

  f32x4 vz = {0.f, 0.f, 0.f, 0.f};
  f32x4 acc[MF][NF];
  #pragma unroll
  for (int m = 0; m < MF; ++m)
    #pragma unroll
    for (int n = 0; n < NF; ++n) acc[m][n] = vz;

  const int sw = (lr & 7) << 4;
  const int nk = K / BK;
  stage(0, 0);
  __syncthreads();
  int cur = 0;
  for (int k = 0; k < nk; ++k) {
    if (k + 1 < nk) stage(cur ^ 1, (k + 1) * BK);
    #pragma unroll
    for (int kk = 0; kk < 2; ++kk) {
      const int rdo = (kk * 64 + lg * 16) ^ sw;
      bf16x8 af[MF], bfr[NF];
      #pragma unroll
      for (int m = 0; m < MF; ++m) {
        int row = wr * RS + m * 16 + lr;
        af[m] = *(const bf16x8*)((const char*)&At[cur][0] + row * 128 + rdo);
      }
      #pragma unroll
      for (int n = 0; n < NF; ++n) {
        int brow = wc * CS + n * 16 + lr;
        bfr[n] = *(const bf16x8*)((const char*)&Bt[cur][0] + brow * 128 + rdo);
      }
      #pragma unroll
      for (int m = 0; m < MF; ++m)
        #pragma unroll
        for (int n = 0; n < NF; ++n) acc[m][n] = MFMA16(af[m], bfr[n], acc[m][n]);
    }
    __syncthreads();
    cur ^= 1;
  }

  #pragma unroll
  for (int m = 0; m < MF; ++m) {
    int rl = wr * RS + m * 16 + lg * 4;
    #pragma unroll
    for (int n = 0; n < NF; ++n) {
      int col = col0 + wc * CS + n * 16 + lr;
      float bz = bias[col];
      #pragma unroll
      for (int r = 0; r < 4; ++r) {
        int row = row0 + rl + r;
        float v = acc[m][n][r] + bz;
        if (EPI == 1) {
          outf[(size_t)row * N + col] = v;
        } else {
          int b = row >> 11, s = row & 2047;
          int part = col >> 10, d = col & 1023;
          int h = d >> 6, dh = d & 63;
          size_t idx = ((size_t)(b * HH + h) * SS + s) * DH + dh;
          if (part == 0) {
            q_b[idx] = (bf16_t)v;
          } else if (part == 1) {
            k_b[idx] = (bf16_t)v;
            outf[(((size_t)(b * 2 + 0) * HH + h) * SS + s) * DH + dh] = v;  // present K
          } else {
            vt_b[((size_t)(b * HH + h) * DH + dh) * SS + s] = (bf16_t)v;   // V transposed
            outf[(((size_t)(b * 2 + 1) * HH + h) * SS + s) * DH + dh] = v;  // present V
          }
        }
      }
    }
  }
}

// ---------------- flash attention: balanced band-pairs, STATIC indexing ----------------
// grid: x = j (0..15 band pairs), y = B*H. Block j owns bands (31-j, j) of
// 64 q-rows each; frag0 = long band, frag1 = short band (active t <= j).
// Constant 33 tile-frags of work per block -> no causal tail. All per-frag
// state uses compile-time indices (rule #20: runtime-indexed arrays spill).
__global__ __launch_bounds__(256) void attn_fwd(
    const bf16_t* __restrict__ q_b, const bf16_t* __restrict__ k_b,
    const bf16_t* __restrict__ vt_b, bf16_t* __restrict__ attn_out) {
  __shared__ __align__(16) bf16_t Kt[2][64 * 64];        // [kv][d] 2x8KB
  __shared__ __align__(16) bf16_t Vt[2][64 * 64];        // [d][kv] 2x8KB
  __shared__ __align__(16) bf16_t P_lds[4][32][72];      // [wave][frag*16+q][kv]+pad

  const int bh = blockIdx.y;
  const int j = blockIdx.x;               // pair index; heaviest (j=0) first
  const int qlb = (31 - j) * 64;          // long band base
  const int qsb = j * 64;                 // short band base
  const int tid = threadIdx.x;
  const int w = tid >> 6, l = tid & 63;
  const int lr = l & 15, lg = l >> 4;

  const bf16_t* qb = q_b + (size_t)bh * SS * DH;
  const bf16_t* kb = k_b + (size_t)bh * SS * DH;
  const bf16_t* vt = vt_b + (size_t)bh * DH * SS;

  const int r0 = tid >> 3;
  const int cs = (((tid & 7) * 16) ^ ((r0 & 7) << 4)) >> 1;
  const bf16_t* gk0 = kb + r0 * DH + cs;
  const bf16_t* gk1 = gk0 + 32 * DH;
  const bf16_t* gv0 = vt + (size_t)r0 * SS + cs;
  const bf16_t* gv1 = gv0 + 32 * SS;
  auto stageKV = [&](int buf) {  // stages the NEXT sequential kv tile
    bf16_t* lk = &Kt[buf][w * 512];
    load_lds16(gk0, lk);
    load_lds16(gk1, lk + 2048);
    bf16_t* lv = &Vt[buf][w * 512];
    load_lds16(gv0, lv);
    load_lds16(gv1, lv + 2048);
    gk0 += 64 * DH; gk1 += 64 * DH; gv0 += 64; gv1 += 64;
  };

  const int qrow0 = qlb + w * 16 + lr;  // frag 0: long band
  const int qrow1 = qsb + w * 16 + lr;  // frag 1: short band
  bf16x8 qf[2][2];
  qf[0][0] = *(const bf16x8*)&qb[(size_t)qrow0 * DH + lg * 8];
  qf[0][1] = *(const bf16x8*)&qb[(size_t)qrow0 * DH + 32 + lg * 8];
  qf[1][0] = *(const bf16x8*)&qb[(size_t)qrow1 * DH + lg * 8];
  qf[1][1] = *(const bf16x8*)&qb[(size_t)qrow1 * DH + 32 + lg * 8];

  bf16x8 ones;
  #pragma unroll
  for (int jj = 0; jj < 8; ++jj) ones[jj] = (bf16_t)1.0f;

  f32x4 vzero = {0.f, 0.f, 0.f, 0.f};
  f32x4 oacc[2][4];
  #pragma unroll
  for (int q = 0; q < 2; ++q)
    #pragma unroll
    for (int d = 0; d < 4; ++d) oacc[q][d] = vzero;
  float m_run[2] = {-1e30f, -1e30f}, l_run[2] = {0.f, 0.f};

  const float SCL = 0.125f * 1.4426950408889634f;  // 1/sqrt(64) * log2(e)
  const int sw = (lr & 7) << 4;
  const int rd0 = (lg * 16) ^ sw;
  const int rd1 = (64 + lg * 16) ^ sw;

  float sc[2][4][4];
  bf16x8 pf[2][2];

  // softmax body for frag Q (compile-time index; wave-uniform caller gate)
  auto softmax_frag = [&](auto qt) {
    constexpr int q = decltype(qt)::v;
    float tm = fmaxf(fmaxf(sc[q][0][0], sc[q][0][1]), sc[q][0][2]);
    tm = fmaxf(fmaxf(tm, sc[q][0][3]), sc[q][1][0]);
    tm = fmaxf(fmaxf(tm, sc[q][1][1]), sc[q][1][2]);
    tm = fmaxf(fmaxf(tm, sc[q][1][3]), sc[q][2][0]);
    tm = fmaxf(fmaxf(tm, sc[q][2][1]), sc[q][2][2]);
    tm = fmaxf(fmaxf(tm, sc[q][2][3]), sc[q][3][0]);
    tm = fmaxf(fmaxf(tm, sc[q][3][1]), sc[q][3][2]);
    tm = fmaxf(tm, sc[q][3][3]);
    tm = fmaxf(tm, __shfl_xor(tm, 16));
    tm = fmaxf(tm, __shfl_xor(tm, 32));
    if (!__all(tm <= m_run[q] + 44.0f)) {   // defer-max (T13)
      float mnew = fmaxf(m_run[q], tm);
      float alpha = fast_exp2((m_run[q] - mnew) * SCL);
      l_run[q] *= alpha;
      #pragma unroll
      for (int d = 0; d < 4; ++d) oacc[q][d] *= alpha;
      m_run[q] = mnew;
    }
    float mneg = m_run[q] * (-SCL);
    #pragma unroll
    for (int kvf = 0; kvf < 4; ++kvf) {
      float p0 = fast_exp2(__builtin_fmaf(sc[q][kvf][0], SCL, mneg));
      float p1 = fast_exp2(__builtin_fmaf(sc[q][kvf][1], SCL, mneg));
      float p2 = fast_exp2(__builtin_fmaf(sc[q][kvf][2], SCL, mneg));
      float p3 = fast_exp2(__builtin_fmaf(sc[q][kvf][3], SCL, mneg));
      uint2 pk;
      pk.x = cvt_pk_bf16(p0, p1);
      pk.y = cvt_pk_bf16(p2, p3);
      *(uint2*)&P_lds[w][q * 16 + lr][kvf * 16 + lg * 4] = pk;
    }
  };
  // P-frag read + l-sum via ones-MFMA for frag Q (compile-time index)
  auto read_p_frag = [&](auto qt) {
    constexpr int q = decltype(qt)::v;
    pf[q][0] = *(const bf16x8*)&P_lds[w][q * 16 + lr][lg * 8];
    pf[q][1] = *(const bf16x8*)&P_lds[w][q * 16 + lr][32 + lg * 8];
    f32x4 ls = vzero;
    ls = MFMA16(ones, pf[q][0], ls);
    ls = MFMA16(ones, pf[q][1], ls);
    l_run[q] += ls[0];
  };

  const int nkv = 32 - j;  // tiles for the long band
  stageKV(0);
  __syncthreads();
  int cur = 0;
  for (int t = 0; t < nkv; ++t) {
    const int kv0 = t * 64;
    if (t + 1 < nkv) stageKV(cur ^ 1);  // prefetch next tile
    const bool act1 = (t <= j);         // short band active (wave-uniform)

    // ---- QK^T (swapped): lane col = q, D-row = kv; RAW scores ----
    #pragma unroll
    for (int kvf = 0; kvf < 4; ++kvf) {
      const char* kbase = (const char*)&Kt[cur][0] + (kvf * 16 + lr) * 128;
      bf16x8 kf0 = *(const bf16x8*)(kbase + rd0);
      bf16x8 kf1 = *(const bf16x8*)(kbase + rd1);
      {
        f32x4 a = vzero;
        a = MFMA16(kf0, qf[0][0], a);
        a = MFMA16(kf1, qf[0][1], a);
        #pragma unroll
        for (int r = 0; r < 4; ++r) sc[0][kvf][r] = a[r];
      }
      if (act1) {
        f32x4 a = vzero;
        a = MFMA16(kf0, qf[1][0], a);
        a = MFMA16(kf1, qf[1][1], a);
        #pragma unroll
        for (int r = 0; r < 4; ++r) sc[1][kvf][r] = a[r];
      }
    }
    // causal masks (wave-uniform gates; trigger only on diagonal tiles)
    if (kv0 + 63 > qlb + w * 16) {
      int dthr = qrow0 - kv0;
      #pragma unroll
      for (int kvf = 0; kvf < 4; ++kvf)
        #pragma unroll
        for (int r = 0; r < 4; ++r) {
          int kvl = kvf * 16 + lg * 4 + r;
          if (kvl > dthr) sc[0][kvf][r] = -1e30f;
        }
    }
    if (act1 && kv0 + 63 > qsb + w * 16) {
      int dthr = qrow1 - kv0;
      #pragma unroll
      for (int kvf = 0; kvf < 4; ++kvf)
        #pragma unroll
        for (int r = 0; r < 4; ++r) {
          int kvl = kvf * 16 + lg * 4 + r;
          if (kvl > dthr) sc[1][kvf][r] = -1e30f;
        }
    }

    // ---- online softmax (static frag indices; frag1 gated wave-uniform) ----
    softmax_frag(QTag<0>{});
    if (act1) softmax_frag(QTag<1>{});

    // ---- read P frags; l-sum via ones-MFMA ----
    read_p_frag(QTag<0>{});
    if (act1) read_p_frag(QTag<1>{});

    // ---- PV (T5 setprio) ----
    __builtin_amdgcn_s_setprio(1);
    #pragma unroll
    for (int d = 0; d < 4; ++d) {
      const char* vbase = (const char*)&Vt[cur][0] + (d * 16 + lr) * 128;
      bf16x8 vf0 = *(const bf16x8*)(vbase + rd0);
      bf16x8 vf1 = *(const bf16x8*)(vbase + rd1);
      oacc[0][d] = MFMA16(vf0, pf[0][0], oacc[0][d]);
      oacc[0][d] = MFMA16(vf1, pf[0][1], oacc[0][d]);
      if (act1) {
        oacc[1][d] = MFMA16(vf0, pf[1][0], oacc[1][d]);
        oacc[1][d] = MFMA16(vf1, pf[1][1], oacc[1][d]);
      }
    }
    __builtin_amdgcn_s_setprio(0);
    __syncthreads();
    cur ^= 1;
  }

  // ---- epilogue: merge heads into [B*S, D] bf16 ----
  const int b = bh >> 4, h = bh & 15;
  #pragma unroll
  for (int q = 0; q < 2; ++q) {
    float inv_l = 1.f / l_run[q];
    int qrow = q ? qrow1 : qrow0;
    #pragma unroll
    for (int d = 0; d < 4; ++d)
      #pragma unroll
      for (int r = 0; r < 4; ++r) {
        int dd = d * 16 + lg * 4 + r;
        attn_out[((size_t)(b * SS + qrow)) * DD + h * DH + dd] =
            (bf16_t)(oacc[q][d][r] * inv_l);
      }
  }
}

// ---------------- launcher ----------------
extern "C" void kernel_launch(void* const* d_in, const int* in_sizes, int n_in,
                              void* d_out, int out_size, void* d_ws, size_t ws_size,
                              hipStream_t stream) {
  const float* x = (const float*)d_in[0];
  const float* c_attn_w = (const float*)d_in[1];
  const float* c_attn_b = (const float*)d_in[2];
  const float* c_proj_w = (const float*)d_in[3];
  const float* c_proj_b = (const float*)d_in[4];

  float* out = (float*)d_out;                       // a: [B,S,D]
  float* present = out + (size_t)BB * SS * DD;      // present: [B,2,H,S,Dh]

  char* ws = (char*)d_ws;
  bf16_t* xb     = (bf16_t*)(ws + 0);               //  8.4 MB  x as bf16 [M,K]
  bf16_t* wqkvT  = (bf16_t*)(ws + 8388608);         //  6.3 MB  [3072,1024]
  bf16_t* wprojT = (bf16_t*)(ws + 14680064);        //  2.1 MB  [1024,1024]
  bf16_t* q_b    = (bf16_t*)(ws + 16777216);        //  8.4 MB  [B,H,S,64]
  bf16_t* k_b    = (bf16_t*)(ws + 25165824);        //  8.4 MB  [B,H,S,64]
  bf16_t* vt_b   = (bf16_t*)(ws + 33554432);        //  8.4 MB  [B,H,64,S]
  bf16_t* attn_o = (bf16_t*)(ws + 41943040);        //  8.4 MB  [M,D]

  // 1. x -> bf16
  cvt_f32_to_bf16<<<(MM * DD / 4 + 255) / 256, 256, 0, stream>>>(x, xb, MM * DD / 4);
  // 2. weight transposes
  transpose_f32_to_bf16<<<dim3(3 * DD / 32, DD / 32), dim3(32, 8), 0, stream>>>(
      c_attn_w, wqkvT, DD, 3 * DD);
  transpose_f32_to_bf16<<<dim3(DD / 32, DD / 32), dim3(32, 8), 0, stream>>>(
      c_proj_w, wprojT, DD, DD);
  // 3. QKV GEMM [4096,1024]x[1024,3072]: 256x192 tile, grid 16x16 = 256 blocks
  gemm2<256, 192, 4, 2, 0><<<dim3(3 * DD / 192, MM / 256), 512, 0, stream>>>(
      xb, wqkvT, c_attn_b, present, q_b, k_b, vt_b, MM, 3 * DD, DD);
  // 4. flash attention: 16 balanced band-pairs x 32 (b,h)
  attn_fwd<<<dim3(16, BB * HH), 256, 0, stream>>>(q_b, k_b, vt_b, attn_o);
  // 5. output projection [4096,1024]x[1024,1024]: 128x128 tile, grid 256 blocks
  gemm2<128, 128, 2, 4, 1><<<dim3(DD / 128, MM / 128), 512, 0, stream>>>(
      attn_o, wprojT, c_proj_b, out, nullptr, nullptr, nullptr, MM, DD, DD);
}